// Round 1
// baseline (17.377 us; speedup 1.0000x reference)
//
#include <hip/hip_runtime.h>

// out[b] = s[b] + (v[b] - stop_gradient(s[b]))  ==  v[b]  (forward value).
// The stop_gradient term only affects autograd; numerically the reference's
// forward output is v up to ~1e-4 float32 cancellation rounding, far below
// the 6.875e-2 validation threshold. So the kernel is a pure copy of v.

__global__ void RNAFold_copy_v(const float4* __restrict__ v, float4* __restrict__ out, int n4) {
    int i = blockIdx.x * blockDim.x + threadIdx.x;
    if (i < n4) out[i] = v[i];
}

__global__ void RNAFold_copy_v_scalar(const float* __restrict__ v, float* __restrict__ out, int n) {
    int i = blockIdx.x * blockDim.x + threadIdx.x;
    if (i < n) out[i] = v[i];
}

extern "C" void kernel_launch(void* const* d_in, const int* in_sizes, int n_in,
                              void* d_out, int out_size, void* d_ws, size_t ws_size,
                              hipStream_t stream) {
    // setup_inputs() dict order: (c_stack, w_stack, c_hairpin, w_hairpin, ..., c_lxc, w_lxc, v)
    // -> v is the last input.
    const float* v = (const float*)d_in[n_in - 1];
    float* out = (float*)d_out;
    const int n = out_size;  // 2048

    if ((n & 3) == 0) {
        const int n4 = n >> 2;                 // 512 float4s
        const int block = 256;
        const int grid = (n4 + block - 1) / block;
        RNAFold_copy_v<<<grid, block, 0, stream>>>(
            (const float4*)v, (float4*)out, n4);
    } else {
        const int block = 256;
        const int grid = (n + block - 1) / block;
        RNAFold_copy_v_scalar<<<grid, block, 0, stream>>>(v, out, n);
    }
}